// Round 1
// baseline (489.828 us; speedup 1.0000x reference)
//
#include <hip/hip_runtime.h>

// Dims fixed by the problem: L=13, B=16, S=512, D=768, W=256.
#define L_DIM 13
#define B_DIM 16
#define S_DIM 512
#define D_DIM 768
#define W_DIM 256

// Words per block. 16 words => W/16 = 16 chunks/sentence, grid = 16*16*13 =
// 3328 blocks (vs 53248 before). Avg chunk span = 16 * S/W = 32 rows => real
// streaming loop per block instead of 2-iteration churn.
#define WPB 16
#define NCHUNK (W_DIM / WPB)

typedef float v4f __attribute__((ext_vector_type(4)));

// Kernel A: precompute word spans. For each (b, w), binary-search the sorted
// seg row for [start, end). 4096 entries -> int2 table in d_ws. Runs in ~2 µs.
// (d_ws is re-poisoned to 0xAA before every launch, so this must run each call.)
__global__ __launch_bounds__(256) void span_kernel(
    const int* __restrict__ seg,    // [B, S] sorted ascending per row
    int2* __restrict__ spans)       // [B, W]
{
    const int idx = blockIdx.x * 256 + threadIdx.x;   // 0 .. B*W-1
    const int b = idx >> 8;                           // idx / W_DIM
    const int w = idx & (W_DIM - 1);
    const int* srow = seg + b * S_DIM;

    int lo = 0, hi = S_DIM;
    while (lo < hi) { int m = (lo + hi) >> 1; if (srow[m] < w) lo = m + 1; else hi = m; }
    const int start = lo;
    hi = S_DIM;
    while (lo < hi) { int m = (lo + hi) >> 1; if (srow[m] < w + 1) lo = m + 1; else hi = m; }
    spans[idx] = make_int2(start, lo);
}

// Kernel B: one block per (l, b, 16-word chunk); 192 threads * float4 = D=768.
//
// Key property of sorted segment ids: end(w) == start(w+1), so the chunk's 16
// words cover ONE contiguous row range [sp[0].x, sp[15].y). We stream that
// range through a 4-deep rotating register prefetch pipeline that is carried
// ACROSS word boundaries — every inner iteration issues exactly one new row
// load and consumes the oldest (steady state vmcnt(3), 4 rows in flight per
// wave). Word boundaries only flush the accumulator, never the pipeline.
// This replaces 53248 blocks whose loop compiled to one-outstanding-load
// (load -> waitcnt vmcnt(0) -> add, ~2 trips) with 3328 blocks doing ~32-row
// streams at 4x the memory-level parallelism and 1/16th the dispatch churn.
__global__ __launch_bounds__(192) void segpool_kernel(
    const float* __restrict__ hs,     // [L, B, S, D]
    const int2* __restrict__ spans,   // [B, W]
    float* __restrict__ out)          // [L, B, W, D]
{
    const int wc = blockIdx.x;        // word chunk within sentence
    const int b  = blockIdx.y;
    const int l  = blockIdx.z;
    const int w0 = wc * WPB;
    const int t  = threadIdx.x;       // 0..191, float4 lane within the row

    // Span table is hot in L2 (32 KB, reused by all 13 layers) — normal loads.
    const int2* __restrict__ sp = spans + b * W_DIM + w0;

    const v4f* __restrict__ base =
        (const v4f*)(hs + ((size_t)l * B_DIM + b) * (size_t)(S_DIM * D_DIM)) + t;
    v4f* __restrict__ obase =
        (v4f*)(out + (((size_t)l * B_DIM + b) * (size_t)W_DIM + w0) * D_DIM) + t;

    int s = sp[0].x;                  // first row of the chunk (block-uniform)

    // Prefetch clamps to the last row of this (l,b) slab: never OOB, and the
    // few overshoot rows belong to the neighboring chunk (likely L2-resident).
#define ROW(si)                                                               \
    __builtin_nontemporal_load(                                               \
        base + (size_t)((si) < (S_DIM - 1) ? (si) : (S_DIM - 1)) * (D_DIM / 4))

    v4f v0 = ROW(s);
    v4f v1 = ROW(s + 1);
    v4f v2 = ROW(s + 2);
    v4f v3 = ROW(s + 3);

    // Fully unrolled so all 16 span-end loads hoist to block entry instead of
    // serializing the 16 word loops.
#pragma unroll
    for (int w = 0; w < WPB; ++w) {
        const int e = sp[w].y;        // end row of word w0+w (== start of next)
        v4f acc = {0.f, 0.f, 0.f, 0.f};
        while (s < e) {               // block-uniform trip count: no divergence
            acc += v0;
            v0 = v1; v1 = v2; v2 = v3;
            v3 = ROW(s + 4);
            ++s;
        }
        // Always write (zeros for empty words) — d_out is re-poisoned each launch.
        __builtin_nontemporal_store(acc, obase + (size_t)w * (D_DIM / 4));
    }
#undef ROW
}

extern "C" void kernel_launch(void* const* d_in, const int* in_sizes, int n_in,
                              void* d_out, int out_size, void* d_ws, size_t ws_size,
                              hipStream_t stream) {
    const float* hs  = (const float*)d_in[0];   // hidden_states [L,B,S,D] f32
    const int*   seg = (const int*)d_in[1];     // segment_ids [B,S] i32
    float* out  = (float*)d_out;                // [L,B,W,D] f32
    int2*  spans = (int2*)d_ws;                 // [B,W] = 32 KB scratch

    span_kernel<<<(B_DIM * W_DIM) / 256, 256, 0, stream>>>(seg, spans);

    dim3 grid(NCHUNK, B_DIM, L_DIM);            // 3328 blocks
    segpool_kernel<<<grid, 192, 0, stream>>>(hs, spans, out);
}